// Round 1
// baseline (1085.348 us; speedup 1.0000x reference)
//
#include <hip/hip_runtime.h>

// Problem constants (from reference): N=100000 nodes, E=1600000 edges, D=48.
constexpr int N_NODES = 100000;
constexpr int D = 48;            // D_IN == D_OUT == 48
constexpr int QPR = D / 4;       // 12 float4 quads per row

// ---------------------------------------------------------------------------
// Kernel 1: xw = x @ w   (x: [N,48] f32, w: [48,48] f32 staged in LDS)
// One thread computes one float4 (4 consecutive output cols) of one row.
// ---------------------------------------------------------------------------
__global__ __launch_bounds__(256) void gemm_xw(
    const float* __restrict__ x, const float* __restrict__ w,
    float4* __restrict__ xw) {
  __shared__ float wlds[D * D];
  for (int i = threadIdx.x; i < D * D; i += 256) wlds[i] = w[i];
  __syncthreads();

  int id = blockIdx.x * 256 + threadIdx.x;     // [0, N*12)
  if (id >= N_NODES * QPR) return;
  int row = id / QPR;
  int q   = id - row * QPR;

  const float* xr = x + row * D;
  float4 acc = make_float4(0.f, 0.f, 0.f, 0.f);
#pragma unroll
  for (int k = 0; k < D; ++k) {
    float xv = xr[k];  // broadcast across the 12 threads sharing this row (L1)
    float4 wv = *reinterpret_cast<const float4*>(&wlds[k * D + q * 4]);
    acc.x = fmaf(xv, wv.x, acc.x);
    acc.y = fmaf(xv, wv.y, acc.y);
    acc.z = fmaf(xv, wv.z, acc.z);
    acc.w = fmaf(xv, wv.w, acc.w);
  }
  xw[id] = acc;
}

// ---------------------------------------------------------------------------
// Kernel 2: edge scatter. 12 threads per edge, each owns 4 cols.
// out[dst*48 + c] += adj_vals[e] * xw[src*48 + c]
// ---------------------------------------------------------------------------
__global__ __launch_bounds__(256) void scatter_edges(
    const float4* __restrict__ xw,
    const int* __restrict__ esrc, const int* __restrict__ edst,
    const float* __restrict__ evals, float* __restrict__ out, int n_edges) {
  int id = blockIdx.x * 256 + threadIdx.x;     // [0, E*12)
  if (id >= n_edges * QPR) return;
  int e = id / QPR;
  int q = id - e * QPR;

  int s = esrc[e];
  int d = edst[e];
  float a = evals[e];
  float4 v = xw[s * QPR + q];

  float* o = out + d * D + q * 4;
  unsafeAtomicAdd(o + 0, a * v.x);
  unsafeAtomicAdd(o + 1, a * v.y);
  unsafeAtomicAdd(o + 2, a * v.z);
  unsafeAtomicAdd(o + 3, a * v.w);
}

// ---------------------------------------------------------------------------
// Kernel 3: out = relu(out + b)  (vectorized float4)
// ---------------------------------------------------------------------------
__global__ __launch_bounds__(256) void bias_relu(
    float4* __restrict__ out, const float4* __restrict__ b4) {
  int id = blockIdx.x * 256 + threadIdx.x;     // [0, N*12)
  if (id >= N_NODES * QPR) return;
  int q = id % QPR;
  float4 v = out[id];
  float4 bb = b4[q];
  v.x = fmaxf(v.x + bb.x, 0.f);
  v.y = fmaxf(v.y + bb.y, 0.f);
  v.z = fmaxf(v.z + bb.z, 0.f);
  v.w = fmaxf(v.w + bb.w, 0.f);
  out[id] = v;
}

// ---------------------------------------------------------------------------
extern "C" void kernel_launch(void* const* d_in, const int* in_sizes, int n_in,
                              void* d_out, int out_size, void* d_ws, size_t ws_size,
                              hipStream_t stream) {
  const float* x     = (const float*)d_in[0];   // [N, 48]
  const float* w     = (const float*)d_in[1];   // [48, 48]
  const float* b     = (const float*)d_in[2];   // [48]
  const int*   esrc  = (const int*)d_in[3];     // [E]
  const int*   edst  = (const int*)d_in[4];     // [E]
  const float* evals = (const float*)d_in[5];   // [E]
  float* out = (float*)d_out;                   // [N, 48]

  const int n_edges = in_sizes[3];

  // workspace: xw [N,48] f32 (19.2 MB)
  float4* xw = (float4*)d_ws;

  // out is re-poisoned to 0xAA before every launch -> zero it (accumulator).
  hipMemsetAsync(out, 0, (size_t)N_NODES * D * sizeof(float), stream);

  {
    int work = N_NODES * QPR;
    gemm_xw<<<(work + 255) / 256, 256, 0, stream>>>(x, w, xw);
  }
  {
    int work = n_edges * QPR;
    scatter_edges<<<(work + 255) / 256, 256, 0, stream>>>(
        xw, esrc, edst, evals, out, n_edges);
  }
  {
    int work = N_NODES * QPR;
    bias_relu<<<(work + 255) / 256, 256, 0, stream>>>(
        (float4*)out, (const float4*)b);
  }
}

// Round 3
// 340.461 us; speedup vs baseline: 3.1879x; 3.1879x over previous
//
#include <hip/hip_runtime.h>

// N=100000 nodes, E=1600000 edges, D_IN=D_OUT=48.
constexpr int N_NODES = 100000;
constexpr int D = 48;
constexpr int QPR = D / 4;       // 12 float4 quads per row
constexpr int SCAN_B = 256;      // scan block size
constexpr int NB = (N_NODES + SCAN_B - 1) / SCAN_B;  // 391 blocks

// ---------------------------------------------------------------------------
// Kernel 1: xw = x @ w   (w staged in LDS; one thread = one float4 of a row)
// ---------------------------------------------------------------------------
__global__ __launch_bounds__(256) void gemm_xw(
    const float* __restrict__ x, const float* __restrict__ w,
    float4* __restrict__ xw) {
  __shared__ float wlds[D * D];
  for (int i = threadIdx.x; i < D * D; i += 256) wlds[i] = w[i];
  __syncthreads();

  int id = blockIdx.x * 256 + threadIdx.x;     // [0, N*12)
  if (id >= N_NODES * QPR) return;
  int row = id / QPR;
  int q   = id - row * QPR;

  const float* xr = x + row * D;
  float4 acc = make_float4(0.f, 0.f, 0.f, 0.f);
#pragma unroll
  for (int k = 0; k < D; ++k) {
    float xv = xr[k];
    float4 wv = *reinterpret_cast<const float4*>(&wlds[k * D + q * 4]);
    acc.x = fmaf(xv, wv.x, acc.x);
    acc.y = fmaf(xv, wv.y, acc.y);
    acc.z = fmaf(xv, wv.z, acc.z);
    acc.w = fmaf(xv, wv.w, acc.w);
  }
  xw[id] = acc;
}

// ---------------------------------------------------------------------------
// CSR build: histogram of in-degree by dst
// ---------------------------------------------------------------------------
__global__ __launch_bounds__(256) void hist_dst(
    const int* __restrict__ edst, int* __restrict__ deg, int ne) {
  int i = blockIdx.x * 256 + threadIdx.x;
  if (i < ne) atomicAdd(&deg[edst[i]], 1);
}

// ---------------------------------------------------------------------------
// Scan step 1: per-block exclusive scan of deg -> offs, block totals -> bsums
// ---------------------------------------------------------------------------
__global__ __launch_bounds__(SCAN_B) void scan_block(
    const int* __restrict__ deg, int* __restrict__ offs,
    int* __restrict__ bsums, int n) {
  __shared__ int tmp[SCAN_B];
  int i = blockIdx.x * SCAN_B + threadIdx.x;
  int v = (i < n) ? deg[i] : 0;
  tmp[threadIdx.x] = v;
  __syncthreads();
#pragma unroll
  for (int off = 1; off < SCAN_B; off <<= 1) {
    int t = (threadIdx.x >= off) ? tmp[threadIdx.x - off] : 0;
    __syncthreads();
    tmp[threadIdx.x] += t;
    __syncthreads();
  }
  if (i < n) offs[i] = tmp[threadIdx.x] - v;          // exclusive within block
  if (threadIdx.x == SCAN_B - 1) bsums[blockIdx.x] = tmp[SCAN_B - 1];
}

// ---------------------------------------------------------------------------
// Scan step 2: single-block exclusive scan of the 391 block sums
// ---------------------------------------------------------------------------
__global__ __launch_bounds__(512) void scan_sums(int* __restrict__ bsums, int nb) {
  __shared__ int tmp[512];
  int v = (threadIdx.x < nb) ? bsums[threadIdx.x] : 0;
  tmp[threadIdx.x] = v;
  __syncthreads();
#pragma unroll
  for (int off = 1; off < 512; off <<= 1) {
    int t = (threadIdx.x >= off) ? tmp[threadIdx.x - off] : 0;
    __syncthreads();
    tmp[threadIdx.x] += t;
    __syncthreads();
  }
  if (threadIdx.x < nb) bsums[threadIdx.x] = tmp[threadIdx.x] - v;  // exclusive
}

// ---------------------------------------------------------------------------
// Scan step 3: add block offsets; init cursor = offs
// ---------------------------------------------------------------------------
__global__ __launch_bounds__(SCAN_B) void finalize_offs(
    int* __restrict__ offs, const int* __restrict__ bsums,
    int* __restrict__ cursor, int n) {
  int i = blockIdx.x * SCAN_B + threadIdx.x;
  if (i >= n) return;
  int o = offs[i] + bsums[blockIdx.x];
  offs[i] = o;
  cursor[i] = o;
}

// ---------------------------------------------------------------------------
// CSR fill: entries[pos] = (src, val) bucketed by dst
// ---------------------------------------------------------------------------
__global__ __launch_bounds__(256) void fill_entries(
    const int* __restrict__ esrc, const int* __restrict__ edst,
    const float* __restrict__ evals, int* __restrict__ cursor,
    int2* __restrict__ entries, int ne) {
  int i = blockIdx.x * 256 + threadIdx.x;
  if (i >= ne) return;
  int d = edst[i];
  int p = atomicAdd(&cursor[d], 1);
  int2 en;
  en.x = esrc[i];
  en.y = __float_as_int(evals[i]);
  entries[p] = en;
}

// ---------------------------------------------------------------------------
// Pull-mode gather + bias + relu. 12 threads per node, 4 cols each.
// 2-way unrolled edge loop for MLP (two gather chains in flight).
// ---------------------------------------------------------------------------
__global__ __launch_bounds__(256) void gather_agg(
    const float4* __restrict__ xw, const int* __restrict__ offs,
    const int* __restrict__ deg, const int2* __restrict__ entries,
    const float4* __restrict__ b4, float4* __restrict__ out) {
  int id = blockIdx.x * 256 + threadIdx.x;     // [0, N*12)
  if (id >= N_NODES * QPR) return;
  int node = id / QPR;
  int q    = id - node * QPR;

  int start = offs[node];
  int g     = deg[node];

  float4 acc0 = make_float4(0.f, 0.f, 0.f, 0.f);
  float4 acc1 = make_float4(0.f, 0.f, 0.f, 0.f);
  int k = 0;
  for (; k + 2 <= g; k += 2) {
    int2 e0 = entries[start + k];
    int2 e1 = entries[start + k + 1];
    float a0 = __int_as_float(e0.y);
    float a1 = __int_as_float(e1.y);
    float4 v0 = xw[e0.x * QPR + q];
    float4 v1 = xw[e1.x * QPR + q];
    acc0.x = fmaf(a0, v0.x, acc0.x);
    acc0.y = fmaf(a0, v0.y, acc0.y);
    acc0.z = fmaf(a0, v0.z, acc0.z);
    acc0.w = fmaf(a0, v0.w, acc0.w);
    acc1.x = fmaf(a1, v1.x, acc1.x);
    acc1.y = fmaf(a1, v1.y, acc1.y);
    acc1.z = fmaf(a1, v1.z, acc1.z);
    acc1.w = fmaf(a1, v1.w, acc1.w);
  }
  if (k < g) {
    int2 e0 = entries[start + k];
    float a0 = __int_as_float(e0.y);
    float4 v0 = xw[e0.x * QPR + q];
    acc0.x = fmaf(a0, v0.x, acc0.x);
    acc0.y = fmaf(a0, v0.y, acc0.y);
    acc0.z = fmaf(a0, v0.z, acc0.z);
    acc0.w = fmaf(a0, v0.w, acc0.w);
  }
  float4 bb = b4[q];
  float4 r;
  r.x = fmaxf(acc0.x + acc1.x + bb.x, 0.f);
  r.y = fmaxf(acc0.y + acc1.y + bb.y, 0.f);
  r.z = fmaxf(acc0.z + acc1.z + bb.z, 0.f);
  r.w = fmaxf(acc0.w + acc1.w + bb.w, 0.f);
  out[id] = r;
}

// ---------------------------------------------------------------------------
extern "C" void kernel_launch(void* const* d_in, const int* in_sizes, int n_in,
                              void* d_out, int out_size, void* d_ws, size_t ws_size,
                              hipStream_t stream) {
  const float* x     = (const float*)d_in[0];   // [N, 48]
  const float* w     = (const float*)d_in[1];   // [48, 48]
  const float* b     = (const float*)d_in[2];   // [48]
  const int*   esrc  = (const int*)d_in[3];     // [E]
  const int*   edst  = (const int*)d_in[4];     // [E]
  const float* evals = (const float*)d_in[5];   // [E]
  float* out = (float*)d_out;                   // [N, 48]

  const int ne = in_sizes[3];

  // ---- workspace layout (~33.3 MB) ----
  char* p = (char*)d_ws;
  float4* xw = (float4*)p;            p += (size_t)N_NODES * D * sizeof(float);
  int* deg    = (int*)p;              p += (size_t)N_NODES * sizeof(int);
  int* offs   = (int*)p;              p += (size_t)N_NODES * sizeof(int);
  int* cursor = (int*)p;              p += (size_t)N_NODES * sizeof(int);
  int* bsums  = (int*)p;              p += 512 * sizeof(int);
  p = (char*)(((uintptr_t)p + 15) & ~(uintptr_t)15);
  int2* entries = (int2*)p;           p += (size_t)ne * sizeof(int2);

  // deg must be zero each call (ws is poisoned to 0xAA before every launch)
  hipMemsetAsync(deg, 0, (size_t)N_NODES * sizeof(int), stream);

  // GEMM (xw) — independent of CSR build
  gemm_xw<<<(N_NODES * QPR + 255) / 256, 256, 0, stream>>>(x, w, xw);

  // CSR build
  hist_dst<<<(ne + 255) / 256, 256, 0, stream>>>(edst, deg, ne);
  scan_block<<<NB, SCAN_B, 0, stream>>>(deg, offs, bsums, N_NODES);
  scan_sums<<<1, 512, 0, stream>>>(bsums, NB);
  finalize_offs<<<NB, SCAN_B, 0, stream>>>(offs, bsums, cursor, N_NODES);
  fill_entries<<<(ne + 255) / 256, 256, 0, stream>>>(
      esrc, edst, evals, cursor, entries, ne);

  // Pull-mode aggregate + bias + relu
  gather_agg<<<(N_NODES * QPR + 255) / 256, 256, 0, stream>>>(
      xw, offs, deg, entries, (const float4*)b, (float4*)out);
}